// Round 12
// baseline (144.864 us; speedup 1.0000x reference)
//
#include <hip/hip_runtime.h>
#include <hip/hip_bf16.h>

typedef int i32x4 __attribute__((ext_vector_type(4)));
typedef int i32x16 __attribute__((ext_vector_type(16)));
typedef unsigned char uchar8 __attribute__((ext_vector_type(8)));
typedef unsigned char uchar4v __attribute__((ext_vector_type(4)));
typedef float float4v __attribute__((ext_vector_type(4)));
typedef unsigned long long u64;

#define N_USERS 8192
#define N_ITEMS 4096
#define BATCH   2048
#define TOPK    10

__device__ __forceinline__ void gload16(const unsigned char* src, char* dst) {
    __builtin_amdgcn_global_load_lds(
        (const __attribute__((address_space(1))) unsigned int*)src,
        (__attribute__((address_space(3))) unsigned int*)dst, 16, 0, 0);
}

// ---------------------------------------------------------------------------
// Kernel 0: fp32 (exact 0/1) -> i8 + invn[row] = rsqrt(count). (proven)
// ---------------------------------------------------------------------------
__global__ __launch_bounds__(256)
void convert_rows(const float* __restrict__ A, unsigned char* __restrict__ Ai8,
                  float* __restrict__ invn) {
    __shared__ float wsum[4];
    const int row  = blockIdx.x;
    const int tid  = threadIdx.x;
    const int wave = tid >> 6;
    const int lane = tid & 63;
    const float* src = A + (size_t)row * N_ITEMS;
    unsigned char* dst = Ai8 + (size_t)row * N_ITEMS;
    float s = 0.f;
#pragma unroll
    for (int i = 0; i < 4; ++i) {
        const int col = tid * 4 + i * 1024;
        float4v v = *(const float4v*)(src + col);
        uchar4v o;
#pragma unroll
        for (int j = 0; j < 4; ++j) {
            o[j] = (unsigned char)(v[j] != 0.f);
            s += v[j];
        }
        *(uchar4v*)(dst + col) = o;
    }
#pragma unroll
    for (int o = 32; o > 0; o >>= 1) s += __shfl_down(s, o);
    if (lane == 0) wsum[wave] = s;
    __syncthreads();
    if (tid == 0) {
        float t = wsum[0] + wsum[1] + wsum[2] + wsum[3];
        invn[row] = (t > 0.f) ? (1.0f / sqrtf(t)) : 0.f;
    }
}

// ---------------------------------------------------------------------------
// Kernel 1: 256x256 8-phase i8 GEMM, mfma_i32_32x32x32_i8. RACE FIX vs r11:
// A(t+2) is staged into the CURRENT buffer at S2/S3, so every LDS read of the
// A region must be ISSUED before S2. ph2 now reads A(cbs2)+A(cbs3)+B(cbs2);
// ph3 reads only B(cbs3) (never staged-over in-window). This restores the
// proven 16x16 invariant (reads-issued-before-overwrite-issued). Staging,
// vmcnt schedule, swizzle, epilogue identical to r11.
// ---------------------------------------------------------------------------
#define BAR_MID() do { __builtin_amdgcn_s_barrier(); \
    asm volatile("s_waitcnt lgkmcnt(0)" ::: "memory"); \
    __builtin_amdgcn_sched_barrier(0); \
    __builtin_amdgcn_s_setprio(1); } while (0)

#define BAR_END() do { __builtin_amdgcn_s_setprio(0); \
    __builtin_amdgcn_sched_barrier(0); \
    __builtin_amdgcn_s_barrier(); } while (0)

#define BAR_END_VM4() do { __builtin_amdgcn_s_setprio(0); \
    __builtin_amdgcn_sched_barrier(0); \
    asm volatile("s_waitcnt vmcnt(4)" ::: "memory"); \
    __builtin_amdgcn_sched_barrier(0); \
    __builtin_amdgcn_s_barrier(); } while (0)

#define BAR_END_VM0() do { __builtin_amdgcn_s_setprio(0); \
    __builtin_amdgcn_sched_barrier(0); \
    asm volatile("s_waitcnt vmcnt(0)" ::: "memory"); \
    __builtin_amdgcn_sched_barrier(0); \
    __builtin_amdgcn_s_barrier(); } while (0)

#define RD_A(afr, bo, CB) \
  _Pragma("unroll") for (int m_ = 0; m_ < 4; ++m_) \
    afr[m_] = *(const i32x4*)(lds + (bo) + aBase + m_ * 4096 + (CB));

#define RD_B(bfr, bo, CB) \
  _Pragma("unroll") for (int n_ = 0; n_ < 2; ++n_) \
    bfr[n_] = *(const i32x4*)(lds + (bo) + bBase + n_ * 4096 + (CB));

#define MMA8(afr, bfr) \
  _Pragma("unroll") for (int m_ = 0; m_ < 4; ++m_) \
  _Pragma("unroll") for (int n_ = 0; n_ < 2; ++n_) \
    acc[m_][n_] = __builtin_amdgcn_mfma_i32_32x32x32_i8( \
        afr[m_], bfr[n_], acc[m_][n_], 0, 0, 0);

#define WINDOW(bo, S0, S1, S2, S3, ENDW) do { \
    RD_A(afA, bo, cbs0); RD_B(bfA, bo, cbs0); S0; \
    BAR_MID(); MMA8(afA, bfA); BAR_END(); \
    RD_A(afB, bo, cbs1); RD_B(bfB, bo, cbs1); S1; \
    BAR_MID(); MMA8(afB, bfB); BAR_END(); \
    RD_A(afA, bo, cbs2); RD_A(afC, bo, cbs3); RD_B(bfA, bo, cbs2); S2; \
    BAR_MID(); MMA8(afA, bfA); BAR_END(); \
    RD_B(bfB, bo, cbs3); S3; \
    BAR_MID(); MMA8(afC, bfB); ENDW; \
} while (0)

__global__ __launch_bounds__(512, 2)
void sim_gemm8(const unsigned char* __restrict__ A,
               const int* __restrict__ bidx,
               const float* __restrict__ invn,
               float* __restrict__ sim) {
    __shared__ char lds[131072];

    const int tid  = threadIdx.x;
    const int w    = tid >> 6;
    const int lane = tid & 63;
    const int m0   = blockIdx.y * 256;
    const int n0   = blockIdx.x * 256;
    const int wr = w >> 2, wc = w & 3;

    // 32x32 fragment addressing
    const int lo  = lane & 31;
    const int hi  = lane >> 5;
    const int swz8 = (lane & 7) << 4;
    const int hib  = hi * 16;
    const int cbs0 = (0 * 32 + hib) ^ swz8;
    const int cbs1 = (1 * 32 + hib) ^ swz8;
    const int cbs2 = (2 * 32 + hib) ^ swz8;
    const int cbs3 = (3 * 32 + hib) ^ swz8;
    const int aBase = wr * 16384 + lo * 128;
    const int bBase = 32768 + (wc >> 1) * 16384 + ((wc & 1) * 64 + lo) * 128;

    // staging: wave stages 8 rows x 128 B per gload; source col pre-swizzled
    const int sr = lane >> 3;
    const int swzcolB = ((lane & 7) ^ sr) * 16;      // bytes
    const unsigned char* pA[4];
    const unsigned char* pB[4];
#pragma unroll
    for (int g = 0; g < 4; ++g) {
        const int row = g * 64 + w * 8 + sr;
        pA[g] = A + (size_t)bidx[m0 + row] * N_ITEMS + swzcolB;
        pB[g] = A + (size_t)(n0 + row) * N_ITEMS + swzcolB;
    }

    i32x16 acc[4][2] = {};
    i32x4 afA[4], afB[4], afC[4], bfA[2], bfB[2];

#define STA(U, h) do { \
    char* d_ = lds + (((U) & 1) * 65536) + (h) * 16384 + w * 1024; \
    const int k0_ = (U) * 128; \
    gload16(pA[(h)*2+0] + k0_, d_); \
    gload16(pA[(h)*2+1] + k0_, d_ + 8192); } while (0)

#define STB(U, h) do { \
    char* d_ = lds + (((U) & 1) * 65536) + 32768 + (h) * 16384 + w * 1024; \
    const int k0_ = (U) * 128; \
    gload16(pB[(h)*2+0] + k0_, d_); \
    gload16(pB[(h)*2+1] + k0_, d_ + 8192); } while (0)

    STA(0, 0); STA(0, 1); STB(0, 0); STB(0, 1); STA(1, 0); STA(1, 1);
    asm volatile("s_waitcnt vmcnt(4)" ::: "memory");
    __builtin_amdgcn_s_barrier();

    for (int i = 0; i < 15; ++i) {
        const int t1 = 2 * i + 1, t2 = 2 * i + 2, t3 = 2 * i + 3;
        WINDOW(0,     STB(t1, 0), STB(t1, 1), STA(t2, 0), STA(t2, 1), BAR_END_VM4());
        WINDOW(65536, STB(t2, 0), STB(t2, 1), STA(t3, 0), STA(t3, 1), BAR_END_VM4());
    }
    WINDOW(0,     STB(31, 0), STB(31, 1), (void)0, (void)0, BAR_END_VM0());
    WINDOW(65536, (void)0, (void)0, (void)0, (void)0, BAR_END());

    // C epilogue: normalize + self-mask.
    // C/D 32x32: col = lo, row = (reg&3) + 8*(reg>>2) + 4*hi  [m74/m101]
    float invc2[2];
#pragma unroll
    for (int nf = 0; nf < 2; ++nf) invc2[nf] = invn[n0 + wc * 64 + nf * 32 + lo];
#pragma unroll
    for (int mf = 0; mf < 4; ++mf) {
#pragma unroll
        for (int reg = 0; reg < 16; ++reg) {
            const int brow = m0 + wr * 128 + mf * 32 + (reg & 3) + 8 * (reg >> 2) + 4 * hi;
            const int ub = bidx[brow];
            const float inb = invn[ub];
            float* rp = sim + (size_t)brow * N_USERS;
#pragma unroll
            for (int nf = 0; nf < 2; ++nf) {
                const int nn = n0 + wc * 64 + nf * 32 + lo;
                float v = (float)acc[mf][nf][reg] * inb * invc2[nf];
                if (nn == ub) v = -1e9f;
                rp[nn] = v;
            }
        }
    }
#undef STA
#undef STB
}

// ---------------------------------------------------------------------------
// Kernel 2: select_blend — one block per batch row (unchanged, proven).
// ---------------------------------------------------------------------------
__device__ __forceinline__ u64 packkey(float f, int idx) {
    unsigned u = __float_as_uint(f);
    u = ((int)u < 0) ? ~u : (u | 0x80000000u);
    return ((u64)u << 32) | (unsigned)(~idx);
}

__global__ __launch_bounds__(256)
void select_blend(const float* __restrict__ sim,
                  const unsigned char* __restrict__ Ai8,
                  const float* __restrict__ pred,
                  float* __restrict__ out) {
    __shared__ u64 bvs[256];

    const int b    = blockIdx.x;
    const int tid  = threadIdx.x;
    const int lane = tid & 63;
    const float* srow = sim + (size_t)b * N_USERS;

    u64 cmax[8];
#pragma unroll
    for (int k = 0; k < 8; ++k) {
        const int slot = tid + k * 256;
        float4v f = ((const float4v*)srow)[slot];
        u64 a = packkey(f[0], slot * 4 + 0);
        u64 bb = packkey(f[1], slot * 4 + 1);
        u64 c = packkey(f[2], slot * 4 + 2);
        u64 d = packkey(f[3], slot * 4 + 3);
        u64 ab = a > bb ? a : bb, cd = c > d ? c : d;
        cmax[k] = ab > cd ? ab : cd;
    }
    u64 lmax = cmax[0];
#pragma unroll
    for (int k = 1; k < 8; ++k) lmax = cmax[k] > lmax ? cmax[k] : lmax;
    bvs[tid] = lmax;
    __syncthreads();

    u64 topkeys[TOPK];
#pragma unroll
    for (int it = 0; it < TOPK; ++it) {
        u64 fv = bvs[lane];
#pragma unroll
        for (int g = 1; g < 4; ++g) {
            u64 v2 = bvs[lane + g * 64];
            if (v2 > fv) fv = v2;
        }
#pragma unroll
        for (int o = 1; o < 64; o <<= 1) {
            u64 ok = __shfl_xor(fv, o);
            if (ok > fv) fv = ok;
        }
        topkeys[it] = fv;
        __syncthreads();
        const int widx = (int)(~(unsigned)fv);
        const int slot = widx >> 2;
        if (tid == (slot & 255)) {
            const int kc = slot >> 8;
            float4v f = *(const float4v*)(srow + slot * 4);
            u64 m = 0;
#pragma unroll
            for (int j = 0; j < 4; ++j) {
                u64 kj = packkey(f[j], slot * 4 + j);
                if (kj < fv && kj > m) m = kj;
            }
#pragma unroll
            for (int k = 0; k < 8; ++k) if (k == kc) cmax[k] = m;
            u64 nl = cmax[0];
#pragma unroll
            for (int k = 1; k < 8; ++k) nl = cmax[k] > nl ? cmax[k] : nl;
            bvs[tid] = nl;
        }
        __syncthreads();
    }

    float w[TOPK]; int nid[TOPK];
    float mx = -1e30f;
#pragma unroll
    for (int k = 0; k < TOPK; ++k) {
        unsigned hi2 = (unsigned)(topkeys[k] >> 32);
        unsigned bits = (hi2 & 0x80000000u) ? (hi2 ^ 0x80000000u) : ~hi2;
        w[k] = __uint_as_float(bits);
        nid[k] = (int)(~(unsigned)topkeys[k]);
        mx = fmaxf(mx, w[k]);
    }
    float sumw = 0.f;
#pragma unroll
    for (int k = 0; k < TOPK; ++k) {
        w[k] = __expf((w[k] - mx) * 2.0f);   // 1/TEMP = 2
        sumw += w[k];
    }
    const float scl = 0.3f / sumw;           // fold (1-gamma)
#pragma unroll
    for (int k = 0; k < TOPK; ++k) w[k] *= scl;

    const float* pr = pred + (size_t)b * N_ITEMS;
    float*       po = out  + (size_t)b * N_ITEMS;
#pragma unroll
    for (int h = 0; h < 2; ++h) {
        const int col = h * 2048 + tid * 8;
        float4v p0 = *(const float4v*)(pr + col);
        float4v p1 = *(const float4v*)(pr + col + 4);
        float agg[8];
#pragma unroll
        for (int j = 0; j < 8; ++j) agg[j] = 0.f;
#pragma unroll
        for (int k = 0; k < TOPK; ++k) {
            uchar8 nv = *(const uchar8*)(Ai8 + (size_t)nid[k] * N_ITEMS + col);
#pragma unroll
            for (int j = 0; j < 8; ++j) agg[j] += w[k] * (float)nv[j];
        }
        float4v o0, o1;
#pragma unroll
        for (int j = 0; j < 4; ++j) {
            o0[j] = 0.7f * p0[j] + agg[j];
            o1[j] = 0.7f * p1[j] + agg[j + 4];
        }
        *(float4v*)(po + col)     = o0;
        *(float4v*)(po + col + 4) = o1;
    }
}

extern "C" void kernel_launch(void* const* d_in, const int* in_sizes, int n_in,
                              void* d_out, int out_size, void* d_ws, size_t ws_size,
                              hipStream_t stream) {
    const float* pred = (const float*)d_in[0];
    const float* A    = (const float*)d_in[1];
    const int*   bidx = (const int*)d_in[2];
    float*       out  = (float*)d_out;

    // ws: Ai8 32 MiB | invn 64 KiB | sim f32 64 MiB
    unsigned char* Ai8  = (unsigned char*)d_ws;
    float*         invn = (float*)((char*)d_ws + (size_t)N_USERS * N_ITEMS);
    float*         sim  = (float*)((char*)d_ws + (size_t)N_USERS * N_ITEMS + 65536);

    convert_rows<<<N_USERS, 256, 0, stream>>>(A, Ai8, invn);
    sim_gemm8<<<dim3(N_USERS / 256, BATCH / 256), 512, 0, stream>>>(Ai8, bidx, invn, sim);
    select_blend<<<BATCH, 256, 0, stream>>>(sim, Ai8, pred, out);
}

// Round 13
// 134.734 us; speedup vs baseline: 1.0752x; 1.0752x over previous
//
#include <hip/hip_runtime.h>
#include <hip/hip_bf16.h>

typedef int i32x4 __attribute__((ext_vector_type(4)));
typedef unsigned char uchar8 __attribute__((ext_vector_type(8)));
typedef unsigned char uchar4v __attribute__((ext_vector_type(4)));
typedef float float4v __attribute__((ext_vector_type(4)));
typedef unsigned long long u64;

#define N_USERS 8192
#define N_ITEMS 4096
#define BATCH   2048
#define TOPK    10

__device__ __forceinline__ void gload16(const unsigned char* src, char* dst) {
    __builtin_amdgcn_global_load_lds(
        (const __attribute__((address_space(1))) unsigned int*)src,
        (__attribute__((address_space(3))) unsigned int*)dst, 16, 0, 0);
}

// ---------------------------------------------------------------------------
// Kernel 0: fp32 (exact 0/1) -> i8 + invn[row] = rsqrt(count). (proven)
// ---------------------------------------------------------------------------
__global__ __launch_bounds__(256)
void convert_rows(const float* __restrict__ A, unsigned char* __restrict__ Ai8,
                  float* __restrict__ invn) {
    __shared__ float wsum[4];
    const int row  = blockIdx.x;
    const int tid  = threadIdx.x;
    const int wave = tid >> 6;
    const int lane = tid & 63;
    const float* src = A + (size_t)row * N_ITEMS;
    unsigned char* dst = Ai8 + (size_t)row * N_ITEMS;
    float s = 0.f;
#pragma unroll
    for (int i = 0; i < 4; ++i) {
        const int col = tid * 4 + i * 1024;
        float4v v = *(const float4v*)(src + col);
        uchar4v o;
#pragma unroll
        for (int j = 0; j < 4; ++j) {
            o[j] = (unsigned char)(v[j] != 0.f);
            s += v[j];
        }
        *(uchar4v*)(dst + col) = o;
    }
#pragma unroll
    for (int o = 32; o > 0; o >>= 1) s += __shfl_down(s, o);
    if (lane == 0) wsum[wave] = s;
    __syncthreads();
    if (tid == 0) {
        float t = wsum[0] + wsum[1] + wsum[2] + wsum[3];
        invn[row] = (t > 0.f) ? (1.0f / sqrtf(t)) : 0.f;
    }
}

// ---------------------------------------------------------------------------
// Kernel 1: 256x256 8-phase i8 GEMM (BK=128, mfma_i32_16x16x64_i8), writes
// fp32 sim. Round-10 configuration (proven best: ~54us, 64% of i8 ceiling,
// 0 bank conflicts, FETCH ~= ideal). 32x32 variant (r11/r12) closed: its
// window cannot keep phases <=6 ds_reads without re-reading A after S2.
// ---------------------------------------------------------------------------
#define BAR_MID() do { __builtin_amdgcn_s_barrier(); \
    asm volatile("s_waitcnt lgkmcnt(0)" ::: "memory"); \
    __builtin_amdgcn_sched_barrier(0); \
    __builtin_amdgcn_s_setprio(1); } while (0)

#define BAR_END() do { __builtin_amdgcn_s_setprio(0); \
    __builtin_amdgcn_sched_barrier(0); \
    __builtin_amdgcn_s_barrier(); } while (0)

#define BAR_END_VM4() do { __builtin_amdgcn_s_setprio(0); \
    __builtin_amdgcn_sched_barrier(0); \
    asm volatile("s_waitcnt vmcnt(4)" ::: "memory"); \
    __builtin_amdgcn_sched_barrier(0); \
    __builtin_amdgcn_s_barrier(); } while (0)

#define BAR_END_VM0() do { __builtin_amdgcn_s_setprio(0); \
    __builtin_amdgcn_sched_barrier(0); \
    asm volatile("s_waitcnt vmcnt(0)" ::: "memory"); \
    __builtin_amdgcn_sched_barrier(0); \
    __builtin_amdgcn_s_barrier(); } while (0)

#define RD_A4(dst, bo, mofs) \
  _Pragma("unroll") for (int m_ = 0; m_ < 4; ++m_) { \
    dst[m_*2+0] = *(const i32x4*)(lds + (bo) + arowb + (m_+(mofs))*2048 + cb0); \
    dst[m_*2+1] = *(const i32x4*)(lds + (bo) + arowb + (m_+(mofs))*2048 + cb1); }

#define RD_B2(dst, bo, nofs) \
  _Pragma("unroll") for (int n_ = 0; n_ < 2; ++n_) { \
    dst[n_*2+0] = *(const i32x4*)(lds + (bo) + browb + (n_+(nofs))*2048 + cb0); \
    dst[n_*2+1] = *(const i32x4*)(lds + (bo) + browb + (n_+(nofs))*2048 + cb1); }

#define MMA4x2(afr, bfr, mofs, nofs) \
  _Pragma("unroll") for (int m_ = 0; m_ < 4; ++m_) \
  _Pragma("unroll") for (int n_ = 0; n_ < 2; ++n_) { \
    acc[m_+(mofs)][n_+(nofs)] = __builtin_amdgcn_mfma_i32_16x16x64_i8( \
        afr[m_*2+0], bfr[n_*2+0], acc[m_+(mofs)][n_+(nofs)], 0, 0, 0); \
    acc[m_+(mofs)][n_+(nofs)] = __builtin_amdgcn_mfma_i32_16x16x64_i8( \
        afr[m_*2+1], bfr[n_*2+1], acc[m_+(mofs)][n_+(nofs)], 0, 0, 0); }

#define WINDOW(bo, S0, S1, S2, S3, ENDW) do { \
    RD_A4(af,  bo, 0); RD_B2(bf01, bo, 0); S0; \
    BAR_MID(); MMA4x2(af,  bf01, 0, 0); BAR_END(); \
    RD_B2(bf23, bo, 2); S1; \
    BAR_MID(); MMA4x2(af,  bf23, 0, 2); BAR_END(); \
    RD_A4(af2, bo, 4); S2; \
    BAR_MID(); MMA4x2(af2, bf01, 4, 0); BAR_END(); \
    S3; \
    BAR_MID(); MMA4x2(af2, bf23, 4, 2); ENDW; \
} while (0)

__global__ __launch_bounds__(512, 2)
void sim_gemm8(const unsigned char* __restrict__ A,
               const int* __restrict__ bidx,
               const float* __restrict__ invn,
               float* __restrict__ sim) {
    __shared__ char lds[131072];

    const int tid  = threadIdx.x;
    const int w    = tid >> 6;
    const int lane = tid & 63;
    const int m0   = blockIdx.y * 256;
    const int n0   = blockIdx.x * 256;
    const int wr = w >> 2, wc = w & 3;

    const int fr = lane & 15, ks = lane >> 4;
    const int swz = (fr & 7) << 4;
    const int cb0 = (ks * 16) ^ swz;
    const int cb1 = (ks * 16 + 64) ^ swz;
    const int arowb = wr * 16384 + fr * 128;
    const int browb = 32768 + (wc >> 1) * 16384 + ((wc & 1) * 64 + fr) * 128;

    const int sr = lane >> 3;
    const int swzcolB = ((lane & 7) ^ sr) * 16;      // bytes
    const unsigned char* pA[4];
    const unsigned char* pB[4];
#pragma unroll
    for (int g = 0; g < 4; ++g) {
        const int row = g * 64 + w * 8 + sr;
        pA[g] = A + (size_t)bidx[m0 + row] * N_ITEMS + swzcolB;
        pB[g] = A + (size_t)(n0 + row) * N_ITEMS + swzcolB;
    }

    i32x4 acc[8][4] = {};
    i32x4 af[8], af2[8], bf01[4], bf23[4];

#define STA(U, h) do { \
    char* d_ = lds + (((U) & 1) * 65536) + (h) * 16384 + w * 1024; \
    const int k0_ = (U) * 128; \
    gload16(pA[(h)*2+0] + k0_, d_); \
    gload16(pA[(h)*2+1] + k0_, d_ + 8192); } while (0)

#define STB(U, h) do { \
    char* d_ = lds + (((U) & 1) * 65536) + 32768 + (h) * 16384 + w * 1024; \
    const int k0_ = (U) * 128; \
    gload16(pB[(h)*2+0] + k0_, d_); \
    gload16(pB[(h)*2+1] + k0_, d_ + 8192); } while (0)

    STA(0, 0); STA(0, 1); STB(0, 0); STB(0, 1); STA(1, 0); STA(1, 1);
    asm volatile("s_waitcnt vmcnt(4)" ::: "memory");
    __builtin_amdgcn_s_barrier();

    for (int i = 0; i < 15; ++i) {
        const int t1 = 2 * i + 1, t2 = 2 * i + 2, t3 = 2 * i + 3;
        WINDOW(0,     STB(t1, 0), STB(t1, 1), STA(t2, 0), STA(t2, 1), BAR_END_VM4());
        WINDOW(65536, STB(t2, 0), STB(t2, 1), STA(t3, 0), STA(t3, 1), BAR_END_VM4());
    }
    WINDOW(0,     STB(31, 0), STB(31, 1), (void)0, (void)0, BAR_END_VM0());
    WINDOW(65536, (void)0, (void)0, (void)0, (void)0, BAR_END());

    const int crow_base = m0 + wr * 128 + ks * 4;
    const int ccol_base = n0 + wc * 64 + fr;
#pragma unroll
    for (int mf = 0; mf < 8; ++mf) {
#pragma unroll
        for (int j = 0; j < 4; ++j) {
            const int b  = crow_base + mf * 16 + j;
            const int ub = bidx[b];
            const float inb = invn[ub];
            float* rp = sim + (size_t)b * N_USERS;
#pragma unroll
            for (int nf = 0; nf < 4; ++nf) {
                const int nn = ccol_base + nf * 16;
                float v = (float)acc[mf][nf][j] * inb * invn[nn];
                if (nn == ub) v = -1e9f;
                rp[nn] = v;
            }
        }
    }
#undef STA
#undef STB
}

// ---------------------------------------------------------------------------
// Kernel 2: select_blend — one block per batch row. Top-10 via u64 keys
// (key = monotone(f32)<<32 | ~idx => u64 max == max val, tie lowest idx),
// then softmax(v/0.5), gather 10 i8 rows, blend. (proven)
// ---------------------------------------------------------------------------
__device__ __forceinline__ u64 packkey(float f, int idx) {
    unsigned u = __float_as_uint(f);
    u = ((int)u < 0) ? ~u : (u | 0x80000000u);
    return ((u64)u << 32) | (unsigned)(~idx);
}

__global__ __launch_bounds__(256)
void select_blend(const float* __restrict__ sim,
                  const unsigned char* __restrict__ Ai8,
                  const float* __restrict__ pred,
                  float* __restrict__ out) {
    __shared__ u64 bvs[256];

    const int b    = blockIdx.x;
    const int tid  = threadIdx.x;
    const int lane = tid & 63;
    const float* srow = sim + (size_t)b * N_USERS;

    u64 cmax[8];
#pragma unroll
    for (int k = 0; k < 8; ++k) {
        const int slot = tid + k * 256;
        float4v f = ((const float4v*)srow)[slot];
        u64 a = packkey(f[0], slot * 4 + 0);
        u64 bb = packkey(f[1], slot * 4 + 1);
        u64 c = packkey(f[2], slot * 4 + 2);
        u64 d = packkey(f[3], slot * 4 + 3);
        u64 ab = a > bb ? a : bb, cd = c > d ? c : d;
        cmax[k] = ab > cd ? ab : cd;
    }
    u64 lmax = cmax[0];
#pragma unroll
    for (int k = 1; k < 8; ++k) lmax = cmax[k] > lmax ? cmax[k] : lmax;
    bvs[tid] = lmax;
    __syncthreads();

    u64 topkeys[TOPK];
#pragma unroll
    for (int it = 0; it < TOPK; ++it) {
        u64 fv = bvs[lane];
#pragma unroll
        for (int g = 1; g < 4; ++g) {
            u64 v2 = bvs[lane + g * 64];
            if (v2 > fv) fv = v2;
        }
#pragma unroll
        for (int o = 1; o < 64; o <<= 1) {
            u64 ok = __shfl_xor(fv, o);
            if (ok > fv) fv = ok;
        }
        topkeys[it] = fv;
        __syncthreads();
        const int widx = (int)(~(unsigned)fv);
        const int slot = widx >> 2;
        if (tid == (slot & 255)) {
            const int kc = slot >> 8;
            float4v f = *(const float4v*)(srow + slot * 4);
            u64 m = 0;
#pragma unroll
            for (int j = 0; j < 4; ++j) {
                u64 kj = packkey(f[j], slot * 4 + j);
                if (kj < fv && kj > m) m = kj;
            }
#pragma unroll
            for (int k = 0; k < 8; ++k) if (k == kc) cmax[k] = m;
            u64 nl = cmax[0];
#pragma unroll
            for (int k = 1; k < 8; ++k) nl = cmax[k] > nl ? cmax[k] : nl;
            bvs[tid] = nl;
        }
        __syncthreads();
    }

    float w[TOPK]; int nid[TOPK];
    float mx = -1e30f;
#pragma unroll
    for (int k = 0; k < TOPK; ++k) {
        unsigned hi2 = (unsigned)(topkeys[k] >> 32);
        unsigned bits = (hi2 & 0x80000000u) ? (hi2 ^ 0x80000000u) : ~hi2;
        w[k] = __uint_as_float(bits);
        nid[k] = (int)(~(unsigned)topkeys[k]);
        mx = fmaxf(mx, w[k]);
    }
    float sumw = 0.f;
#pragma unroll
    for (int k = 0; k < TOPK; ++k) {
        w[k] = __expf((w[k] - mx) * 2.0f);   // 1/TEMP = 2
        sumw += w[k];
    }
    const float scl = 0.3f / sumw;           // fold (1-gamma)
#pragma unroll
    for (int k = 0; k < TOPK; ++k) w[k] *= scl;

    const float* pr = pred + (size_t)b * N_ITEMS;
    float*       po = out  + (size_t)b * N_ITEMS;
#pragma unroll
    for (int h = 0; h < 2; ++h) {
        const int col = h * 2048 + tid * 8;
        float4v p0 = *(const float4v*)(pr + col);
        float4v p1 = *(const float4v*)(pr + col + 4);
        float agg[8];
#pragma unroll
        for (int j = 0; j < 8; ++j) agg[j] = 0.f;
#pragma unroll
        for (int k = 0; k < TOPK; ++k) {
            uchar8 nv = *(const uchar8*)(Ai8 + (size_t)nid[k] * N_ITEMS + col);
#pragma unroll
            for (int j = 0; j < 8; ++j) agg[j] += w[k] * (float)nv[j];
        }
        float4v o0, o1;
#pragma unroll
        for (int j = 0; j < 4; ++j) {
            o0[j] = 0.7f * p0[j] + agg[j];
            o1[j] = 0.7f * p1[j] + agg[j + 4];
        }
        *(float4v*)(po + col)     = o0;
        *(float4v*)(po + col + 4) = o1;
    }
}

extern "C" void kernel_launch(void* const* d_in, const int* in_sizes, int n_in,
                              void* d_out, int out_size, void* d_ws, size_t ws_size,
                              hipStream_t stream) {
    const float* pred = (const float*)d_in[0];
    const float* A    = (const float*)d_in[1];
    const int*   bidx = (const int*)d_in[2];
    float*       out  = (float*)d_out;

    // ws: Ai8 32 MiB | invn 64 KiB | sim f32 64 MiB
    unsigned char* Ai8  = (unsigned char*)d_ws;
    float*         invn = (float*)((char*)d_ws + (size_t)N_USERS * N_ITEMS);
    float*         sim  = (float*)((char*)d_ws + (size_t)N_USERS * N_ITEMS + 65536);

    convert_rows<<<N_USERS, 256, 0, stream>>>(A, Ai8, invn);
    sim_gemm8<<<dim3(N_USERS / 256, BATCH / 256), 512, 0, stream>>>(Ai8, bidx, invn, sim);
    select_blend<<<BATCH, 256, 0, stream>>>(sim, Ai8, pred, out);
}